// Round 1
// baseline (294.431 us; speedup 1.0000x reference)
//
#include <hip/hip_runtime.h>
#include <math.h>

#define BB 32
#define NCLS 15
#define HH 256
#define WW 256
#define KK 500
#define HW (HH*WW)                 // 65536
#define NELEM (BB*NCLS*HW)         // 31457280
#define N4 (NELEM/4)               // 7864320 float4s
#define NM (BB*NCLS*16*16)         // 122880 multiplier slots
#define BK (BB*KK)                 // 16000

// Fused main kernel: one block owns a quarter of one (b,c) slab.
// slab = 16384 float4s; 4 blocks/slab -> 1920 blocks x 256 thr,
// 16 float4-pairs per thread in 4 MLP-8 batches. Class (and therefore
// gamma) is block-uniform -> SGPR, no per-quad %15, no per-quad vmcnt-
// polluting constant load (R0 theory: that load forced a vmcnt(0)-style
// drain of the streaming MLP batch).
#define FG 1920
#define FT 256
#define SLAB4 16384                // float4s per (b,c) slab
#define QUART 4096                 // float4s per block
#define BKPB 9                     // bk items per block (1920*9 = 17280 >= 16000)

typedef float v4f __attribute__((ext_vector_type(4)));

// ws layout (floats):
//  f[0] = S  f[1] = num_pos  i[2] = last (init -1)  i[3] = corr block counter
//  f[4 .. 4+BK) = l_bk   f[16384 .. 16384+NM) = multiplier table M (init 1.0)
#define OFF_LBK 4
#define OFF_M   16384

__constant__ float c_gammas[15] = {2.7f,2.1f,2.4f,2.0f,3.0f,2.9f,3.0f,2.5f,
                                   2.1f,2.6f,2.0f,2.1f,2.7f,2.4f,2.2f};

// Raw HW transcendentals (glibc collides with __exp2f/__log2f names):
#define EXP2F(x) __builtin_amdgcn_exp2f(x)
#define LOG2F(x) __builtin_amdgcn_logf(x)
#define LN2 0.69314718055994530942f

__device__ __forceinline__ float elem(float p, float g, float gam, float& np) {
    float t    = 1.0f - g;
    float t2   = t * t;
    float negw = (g < 1.0f) ? t2 * t2 : 0.0f;          // (1-g)^4 * neg_ind
    float pw   = EXP2F(gam * LOG2F(p));                // p^gam (0 -> 0)
    float v    = (LN2 * LOG2F(1.0f - p + 1e-12f)) * pw * negw;
    if (g == 1.0f) {                                   // ~never taken
        np += 1.0f;
        v += (LN2 * LOG2F(p + 1e-12f)) * EXP2F(gam * LOG2F(1.0f - p));
    }
    return v;
}

// Sum of 4 elems, UNSCALED by gamma (gamma is block-uniform, factored out).
__device__ __forceinline__ float elem4(v4f p, v4f g, float gam, float& np) {
    return elem(p.x, g.x, gam, np) + elem(p.y, g.y, gam, np)
         + elem(p.z, g.z, gam, np) + elem(p.w, g.w, gam, np);
}

__device__ __forceinline__ float blockReduceSum(float v) {
    __shared__ float sh[4];
    #pragma unroll
    for (int o = 32; o > 0; o >>= 1) v += __shfl_down(v, o);
    int lane = threadIdx.x & 63, w = threadIdx.x >> 6;
    if (lane == 0) sh[w] = v;
    __syncthreads();
    float r = 0.0f;
    if (threadIdx.x == 0) r = sh[0] + sh[1] + sh[2] + sh[3];
    __syncthreads();
    return r;   // valid on thread 0 only
}

// ---- init: zero scalars, last=-1, corr counter=0, M=1.0 ----
__global__ __launch_bounds__(256) void k_init(float* ws) {
    int i = blockIdx.x * blockDim.x + threadIdx.x;
    if (i == 0) {
        ws[0] = 0.0f;
        ws[1] = 0.0f;
        ((int*)ws)[2] = -1;
        ((int*)ws)[3] = 0;
    }
    if (i < NM) ws[OFF_M + i] = 1.0f;
}

// ---- fused: distributed per-(b,k) preamble + slab streaming sweep ----
__global__ __launch_bounds__(256) void k_fused(const v4f*   __restrict__ pred,
                                               const v4f*   __restrict__ gt,
                                               const float* __restrict__ output,
                                               const int*   __restrict__ mask,
                                               const int*   __restrict__ ind,
                                               const float* __restrict__ target,
                                               const int*   __restrict__ inde,
                                               float* ws) {
    const int tid = threadIdx.x;
    const int blk = blockIdx.x;

    // --- per-(b,k) work, 9 items on lanes 0..8 of wave 0 (was k_bk) ---
    int lastv = -1;
    if (tid < BKPB) {
        int t = blk * BKPB + tid;
        if (t < BK) {
            int b = t / KK;
            int pos = ind[t];                                // 0..HW-1
            const float* ob = output + (size_t)b * 2 * HW;
            float p0 = ob[pos];
            float p1 = ob[HW + pos];
            float d0 = p0 - target[t*2 + 0];
            float d1 = p1 - target[t*2 + 1];
            float a0 = fabsf(d0), a1 = fabsf(d1);
            float h0 = (a0 < 1.0f) ? 0.5f*d0*d0 : a0 - 0.5f;
            float h1 = (a1 < 1.0f) ? 0.5f*d1*d1 : a1 - 0.5f;
            float l  = 0.5f * (h0 + h1);
            ws[OFF_LBK + t] = l;
            if (mask[t] != 0) {
                lastv = t;
                float factor = atanf(l) * 0.63661977236758134308f;  // 2/pi
                int ch = inde[t*3 + 0];
                int yy = inde[t*3 + 1];
                int xx = inde[t*3 + 2];
                int mi = ((b*NCLS + ch)*16 + yy)*16 + xx;
                unsigned int* addr = (unsigned int*)(ws + OFF_M + mi);
                unsigned int old = *addr, assumed;
                do {
                    assumed = old;
                    float nv = __uint_as_float(assumed) * factor;
                    old = atomicCAS(addr, assumed, __float_as_uint(nv));
                } while (old != assumed);
            }
        }
    }
    // items live in lanes 0..8 of wave 0; tree-max over lanes 0..15
    #pragma unroll
    for (int o = 8; o > 0; o >>= 1) lastv = max(lastv, __shfl_down(lastv, o));
    if (tid == 0 && lastv >= 0) atomicMax(((int*)ws) + 2, lastv);

    // --- streaming sweep over this block's slab quarter ---
    const int slab = blk >> 2;              // (b*15 + c)
    const int c    = slab % NCLS;           // SGPR-uniform
    const float gam = c_gammas[c];          // one scalar load per block
    const int base = slab * SLAB4 + (blk & 3) * QUART + tid;

    float acc = 0.0f, np = 0.0f;
    #pragma unroll 1
    for (int k = 0; k < 4; ++k) {
        int i0 = base + k * 1024;
        // 8 independent nt loads, pred/gt interleaved so quad0 only needs
        // vmcnt(6) (6 loads stay in flight under its compute)
        v4f p0 = __builtin_nontemporal_load(pred + i0);
        v4f g0 = __builtin_nontemporal_load(gt   + i0);
        v4f p1 = __builtin_nontemporal_load(pred + i0 + 256);
        v4f g1 = __builtin_nontemporal_load(gt   + i0 + 256);
        v4f p2 = __builtin_nontemporal_load(pred + i0 + 512);
        v4f g2 = __builtin_nontemporal_load(gt   + i0 + 512);
        v4f p3 = __builtin_nontemporal_load(pred + i0 + 768);
        v4f g3 = __builtin_nontemporal_load(gt   + i0 + 768);
        acc += elem4(p0, g0, gam, np);
        acc += elem4(p1, g1, gam, np);
        acc += elem4(p2, g2, gam, np);
        acc += elem4(p3, g3, gam, np);
    }
    acc *= gam;                              // gamma factored out of the sum

    float bs = blockReduceSum(acc);
    if (tid == 0 && bs != 0.0f) atomicAdd(&ws[0], bs);
    float bn = blockReduceSum(np);
    if (tid == 0 && bn != 0.0f) atomicAdd(&ws[1], bn);
}

// ---- correction at scatter-modified locations + fused finalize ----
// grid must be exactly NM/256 = 480 blocks (counter pattern assumes it).
__global__ __launch_bounds__(256) void k_corr(const float* __restrict__ pred,
                                              const float* __restrict__ gt,
                                              float* ws, float* out) {
    int i = blockIdx.x * blockDim.x + threadIdx.x;
    float acc = 0.0f, dummy = 0.0f;
    float m = ws[OFF_M + i];
    if (m != 1.0f) {
        int x  = i & 15;
        int y  = (i >> 4) & 15;
        int bc = i >> 8;
        int c  = bc % NCLS;
        size_t off = ((size_t)bc << 16) + (size_t)(y * WW + x);
        float p = pred[off];
        float g = gt[off];
        float gam = c_gammas[c];
        acc = gam * (elem(p * m, g, gam, dummy) - elem(p, g, gam, dummy));
    }
    float bs = blockReduceSum(acc);
    if (threadIdx.x == 0) {
        if (bs != 0.0f) atomicAdd(&ws[0], bs);
        __threadfence();                                   // flush my add
        int done = atomicAdd(((int*)ws) + 3, 1);
        if (done == gridDim.x - 1) {                       // last block finalizes
            float S  = atomicAdd(&ws[0], 0.0f);            // coherent reads
            float np = atomicAdd(&ws[1], 0.0f);
            int last = ((volatile int*)ws)[2];             // written by k_fused (prior kernel)
            float loss0 = (last >= 0) ? ws[OFF_LBK + last] : 0.0f;
            float loss = loss0 - 0.5f * S;
            out[0] = (np == 0.0f) ? loss : loss / np;
        }
    }
}

extern "C" void kernel_launch(void* const* d_in, const int* in_sizes, int n_in,
                              void* d_out, int out_size, void* d_ws, size_t ws_size,
                              hipStream_t stream) {
    const float* pred   = (const float*)d_in[0];
    const float* gt     = (const float*)d_in[1];
    const float* output = (const float*)d_in[2];
    const int*   mask   = (const int*)d_in[3];
    const int*   ind    = (const int*)d_in[4];
    const float* target = (const float*)d_in[5];
    const int*   inde   = (const int*)d_in[6];
    float* ws  = (float*)d_ws;
    float* out = (float*)d_out;

    k_init <<<(NM + 255)/256, 256, 0, stream>>>(ws);
    k_fused<<<FG, FT, 0, stream>>>((const v4f*)pred, (const v4f*)gt,
                                   output, mask, ind, target, inde, ws);
    k_corr <<<NM/256, 256, 0, stream>>>(pred, gt, ws, out);
}